// Round 1
// baseline (105.685 us; speedup 1.0000x reference)
//
#include <hip/hip_runtime.h>
#include <hip/hip_bf16.h>

// Chamfer distance, B=4, N=M=8192, fp32. Output: scalar sum(min over m) + sum(min over n).
// Strategy: VALU-bound pairwise min. Expansion trick d2 = sq1 + (sq2 - 2*dot), sq1 hoisted
// out of the min. Q tile staged in LDS as float4(x,y,z,sq). R=4 query points per thread to
// amortize LDS broadcast reads. Cross-m-chunk min combined via uint atomicMin (values >= 0).

#define BATCH 4
#define NPTS 8192
#define MS 16              // m-chunks per direction
#define RPT 4              // query points per thread
#define TQ 256             // LDS tile size (points)
#define CHUNK (NPTS / MS)  // 512 m per chunk

__global__ __launch_bounds__(256) void chamfer_min_kernel(
    const float* __restrict__ p1, const float* __restrict__ p2,
    unsigned int* __restrict__ wmin /* [2][BATCH][NPTS] */) {
  const int mchunk = blockIdx.x;           // 0..MS-1
  const int nblk = blockIdx.y;             // 0..NPTS/(RPT*256)-1
  const int zb = blockIdx.z;               // 0..2*BATCH-1
  const int dir = zb >> 2;
  const int b = zb & 3;
  const float* __restrict__ P = dir ? p2 : p1;
  const float* __restrict__ Q = dir ? p1 : p2;
  unsigned int* __restrict__ wm = wmin + ((size_t)dir * BATCH + b) * NPTS;

  const int t = threadIdx.x;

  float px[RPT], py[RPT], pz[RPT], acc[RPT];
#pragma unroll
  for (int r = 0; r < RPT; ++r) {
    const int n = nblk * (RPT * 256) + r * 256 + t;
    const float* pp = P + ((size_t)b * NPTS + n) * 3;
    px[r] = pp[0];
    py[r] = pp[1];
    pz[r] = pp[2];
    acc[r] = INFINITY;  // tracks min of (sq2 - 2*dot); can be negative
  }

  __shared__ float4 sQ[TQ];
  const int mstart = mchunk * CHUNK;

  for (int tile = 0; tile < CHUNK; tile += TQ) {
    const int mi = mstart + tile + t;
    const float* qp = Q + ((size_t)b * NPTS + mi) * 3;
    const float qx = qp[0], qy = qp[1], qz = qp[2];
    const float qs = fmaf(qx, qx, fmaf(qy, qy, qz * qz));
    __syncthreads();
    sQ[t] = make_float4(qx, qy, qz, qs);
    __syncthreads();

#pragma unroll 4
    for (int j = 0; j < TQ; j += 2) {
      const float4 q0 = sQ[j];
      const float4 q1 = sQ[j + 1];
#pragma unroll
      for (int r = 0; r < RPT; ++r) {
        const float t0 = fmaf(px[r], q0.x, fmaf(py[r], q0.y, pz[r] * q0.z));
        const float c0 = fmaf(-2.f, t0, q0.w);
        const float t1 = fmaf(px[r], q1.x, fmaf(py[r], q1.y, pz[r] * q1.z));
        const float c1 = fmaf(-2.f, t1, q1.w);
        acc[r] = fminf(acc[r], fminf(c0, c1));  // folds to v_min3_f32
      }
    }
  }

#pragma unroll
  for (int r = 0; r < RPT; ++r) {
    const int n = nblk * (RPT * 256) + r * 256 + t;
    const float s1 = fmaf(px[r], px[r], fmaf(py[r], py[r], pz[r] * pz[r]));
    const float v = fmaxf(acc[r] + s1, 0.f);  // clamp: keeps uint-ordered atomicMin valid
    atomicMin(&wm[n], __float_as_uint(v));
  }
}

__global__ __launch_bounds__(256) void chamfer_init_kernel(unsigned int* wmin, float* out) {
  const int i = blockIdx.x * 256 + threadIdx.x;
  if (i < 2 * BATCH * NPTS) wmin[i] = 0x7F800000u;  // +inf
  if (i == 0) out[0] = 0.f;
}

__global__ __launch_bounds__(256) void chamfer_reduce_kernel(const unsigned int* __restrict__ wmin,
                                                             float* __restrict__ out) {
  // 2*BATCH*NPTS = 65536 elements; 64 blocks x 256 threads x 4 elems
  float s = 0.f;
  const int base = blockIdx.x * 1024 + threadIdx.x;
#pragma unroll
  for (int k = 0; k < 4; ++k) s += __uint_as_float(wmin[base + k * 256]);
#pragma unroll
  for (int off = 32; off > 0; off >>= 1) s += __shfl_down(s, off, 64);
  __shared__ float wsum[4];
  const int lane = threadIdx.x & 63, wid = threadIdx.x >> 6;
  if (lane == 0) wsum[wid] = s;
  __syncthreads();
  if (threadIdx.x == 0) atomicAdd(out, wsum[0] + wsum[1] + wsum[2] + wsum[3]);
}

extern "C" void kernel_launch(void* const* d_in, const int* in_sizes, int n_in,
                              void* d_out, int out_size, void* d_ws, size_t ws_size,
                              hipStream_t stream) {
  const float* p1 = (const float*)d_in[0];
  const float* p2 = (const float*)d_in[1];
  float* out = (float*)d_out;
  unsigned int* wmin = (unsigned int*)d_ws;  // 2*BATCH*NPTS uints = 256 KB

  // 1) init ws mins to +inf, out to 0 (harness poisons both with 0xAA)
  chamfer_init_kernel<<<dim3(2 * BATCH * NPTS / 256), dim3(256), 0, stream>>>(wmin, out);

  // 2) fused both-direction min kernel
  dim3 grid(MS, NPTS / (RPT * 256), 2 * BATCH);
  chamfer_min_kernel<<<grid, dim3(256), 0, stream>>>(p1, p2, wmin);

  // 3) final sum of 65536 mins
  chamfer_reduce_kernel<<<dim3(64), dim3(256), 0, stream>>>(wmin, out);
}